// Round 3
// baseline (219.065 us; speedup 1.0000x reference)
//
#include <hip/hip_runtime.h>
#include <math.h>

#define BATCH 4
#define CH    256   // feature channels == depth of sampled volume
#define HH    128
#define WW    128
#define PC    256   // para channels
#define PI_F  3.14159f
#define PLANE (HH * WW)   // 16384 floats = 64 KiB

// ---------------------------------------------------------------------------
// Fully fused AdaAT: one block per (b,c) plane, 1024 threads.
//  1. issue 8 float4 staging loads (both z-planes) into registers
//  2. compute p = relu(pc @ W1 + b1) (redundant per block; W1 is L2-resident)
//  3. waves 0-3 compute the 4 head dot-products for column c (shfl reduce)
//  4. thread 0 does transcendentals -> fused affine constants in LDS;
//     meanwhile all threads dump staged registers into swizzled LDS planes
//  5. gather loop: wave = 8x8 pixel tile, 16 tiles/wave, full trilinear
// LDS swizzle: addr = y*128 + (x ^ ((y&3)<<3)) — non-linear, no rotation
// angle can degenerate a whole wave (worst ~4-way, typical <=2-way = free).
// ---------------------------------------------------------------------------
__global__ __launch_bounds__(1024)
void adaat_fused_kernel(const float* __restrict__ fm,
                        const float* __restrict__ pc,
                        const float* __restrict__ W1, const float* __restrict__ b1,
                        const float* __restrict__ Ws, const float* __restrict__ bs,
                        const float* __restrict__ Wr, const float* __restrict__ br,
                        const float* __restrict__ Wt, const float* __restrict__ bt,
                        float* __restrict__ out) {
    __shared__ float lds[2 * PLANE];     // 128 KiB: plane z0, plane z1
    __shared__ float sh_red[1024];
    __shared__ float p_sh[PC];
    __shared__ float sh_head[4];
    __shared__ float sh_par[4];

    const int bc = blockIdx.x;           // b*CH + c
    const int c  = bc & (CH - 1);
    const int b  = bc >> 8;
    const int t  = threadIdx.x;

    // ---- z interpolation (uniform across block) ----
    const float iz  = (256.0f / 255.0f) * (float)c - 0.5f;
    const float z0f = floorf(iz);
    const float fz  = iz - z0f;
    const int   z0  = (int)z0f;
    const float wz0 = (z0 >= 0)       ? (1.0f - fz) : 0.0f;
    const float wz1 = (z0 + 1 < CH)   ? fz          : 0.0f;
    const int   zc0 = max(z0, 0);
    const int   zc1 = min(z0 + 1, CH - 1);

    const float* base  = fm + (size_t)b * (CH * PLANE);
    const float* pl0   = base + (size_t)zc0 * PLANE;
    const float* pl1   = base + (size_t)zc1 * PLANE;

    // ---- 1) staging loads into registers (latency hides behind GEMV) ----
    float4 st[8];
#pragma unroll
    for (int i = 0; i < 8; ++i) {
        const int fi = 4 * (t + 1024 * i);          // 0 .. 32764
        const int f  = fi & (PLANE - 1);
        st[i] = (fi < PLANE) ? *(const float4*)(pl0 + f)
                             : *(const float4*)(pl1 + f);
    }

    // ---- 2) p = relu(pc @ W1 + b1), 4-way k-split over 1024 threads ----
    {
        const int jj = t & 255;
        const int kk = t >> 8;                      // 0..3
        const float* pcb = pc + b * PC + kk * 64;   // wave-uniform -> s_load
        const float* w   = W1 + (kk * 64) * PC + jj;
        float acc = 0.0f;
#pragma unroll 8
        for (int i = 0; i < 64; ++i)
            acc = fmaf(pcb[i], w[i * PC], acc);
        sh_red[t] = acc;
    }
    __syncthreads();
    if (t < 256) {
        const float s = sh_red[t] + sh_red[256 + t] + sh_red[512 + t]
                      + sh_red[768 + t] + b1[t];
        p_sh[t] = fmaxf(s, 0.0f);
    }
    __syncthreads();

    // ---- 3) head dot-products for column c: one wave per head ----
    const int wv = t >> 6;
    const int l  = t & 63;
    if (wv < 4) {
        const float* wp;
        int stride;
        if      (wv == 0) { wp = Ws + c;                  stride = 256; }
        else if (wv == 1) { wp = Wr + c;                  stride = 256; }
        else              { wp = Wt + 2 * c + (wv == 3);  stride = 512; }
        float dot = 0.0f;
#pragma unroll
        for (int m = 0; m < 4; ++m) {
            const int k = l + 64 * m;
            dot = fmaf(p_sh[k], wp[(size_t)k * stride], dot);
        }
#pragma unroll
        for (int off = 32; off >= 1; off >>= 1)
            dot += __shfl_xor(dot, off, 64);
        if (l == 0) sh_head[wv] = dot;
    }
    __syncthreads();

    // ---- 4) thread 0: transcendentals -> fused affine constants ----
    if (t == 0) {
        const float ds = sh_head[0] + bs[c];
        const float dr = sh_head[1] + br[c];
        const float d0 = sh_head[2] + bt[2 * c];
        const float d1 = sh_head[3] + bt[2 * c + 1];
        const float s   = 2.0f / (1.0f + expf(-ds));
        const float ang = tanhf(dr) * PI_F;
        float sa, ca;
        sincosf(ang, &sa, &ca);
        const float A  = s * ca, B = s * sa;
        const float Tx = tanhf(d0), Ty = tanhf(d1);
        // ix = cA*x - cB*y + C0 ; iy = cB*x + cA*y + C1   (pixel-space direct)
        sh_par[0] = A * (128.0f / 127.0f);
        sh_par[1] = B * (128.0f / 127.0f);
        sh_par[2] = 64.0f * (Tx - A + B) + 63.5f;
        sh_par[3] = 64.0f * (Ty - A - B) + 63.5f;
    }
    // ---- all threads: staged registers -> swizzled LDS planes ----
#pragma unroll
    for (int i = 0; i < 8; ++i) {
        const int fi   = 4 * (t + 1024 * i);
        const int pofs = (fi >> 14) * PLANE;        // 0 or PLANE
        const int f    = fi & (PLANE - 1);
        const int y    = f >> 7;
        const int x    = f & (WW - 1);
        const int xs   = x ^ ((y & 3) << 3);        // aligned-4 run stays contiguous
        *(float4*)&lds[pofs + y * WW + xs] = st[i];
    }
    __syncthreads();

    // ---- 5) gather: wave = 8x8 tile, 16 tiles along x-rows of the wave ----
    const float cA = sh_par[0], cB = sh_par[1], C0 = sh_par[2], C1 = sh_par[3];
    const int   xi = l & 7;
    const int   yj = wv * 8 + (l >> 3);
    const float yf = (float)yj;
    float* outp = out + (size_t)bc * PLANE + yj * WW;

#pragma unroll 4
    for (int k = 0; k < 16; ++k) {
        const float xf  = (float)(k * 8 + xi);
        const float ixf = fmaf(cA, xf, fmaf(-cB, yf, C0));
        const float iyf = fmaf(cB, xf, fmaf(cA, yf, C1));
        const float x0f = floorf(ixf);
        const float y0f = floorf(iyf);
        const float fx  = ixf - x0f;
        const float fy  = iyf - y0f;
        // zero-padding masks (corner valid iff index in [0,127])
        const float mx0 = (x0f >= 0.0f  && x0f < 128.0f) ? (1.0f - fx) : 0.0f;
        const float mx1 = (x0f >= -1.0f && x0f < 127.0f) ? fx          : 0.0f;
        const float my0 = (y0f >= 0.0f  && y0f < 128.0f) ? (1.0f - fy) : 0.0f;
        const float my1 = (y0f >= -1.0f && y0f < 127.0f) ? fy          : 0.0f;

        const int x0i = (int)x0f, y0i = (int)y0f;
        const int xc0 = min(max(x0i,     0), WW - 1);
        const int xc1 = min(max(x0i + 1, 0), WW - 1);
        const int yc0 = min(max(y0i,     0), HH - 1);
        const int yc1 = min(max(y0i + 1, 0), HH - 1);

        const int sw0 = (yc0 & 3) << 3;
        const int sw1 = (yc1 & 3) << 3;
        const int a00 = yc0 * WW + (xc0 ^ sw0);
        const int a01 = yc0 * WW + (xc1 ^ sw0);
        const int a10 = yc1 * WW + (xc0 ^ sw1);
        const int a11 = yc1 * WW + (xc1 ^ sw1);

        const float v000 = lds[a00],         v001 = lds[a01];
        const float v010 = lds[a10],         v011 = lds[a11];
        const float v100 = lds[PLANE + a00], v101 = lds[PLANE + a01];
        const float v110 = lds[PLANE + a10], v111 = lds[PLANE + a11];

        const float h00  = mx0 * v000 + mx1 * v001;
        const float h01  = mx0 * v010 + mx1 * v011;
        const float h10  = mx0 * v100 + mx1 * v101;
        const float h11  = mx0 * v110 + mx1 * v111;
        const float bil0 = my0 * h00 + my1 * h01;
        const float bil1 = my0 * h10 + my1 * h11;

        outp[k * 8 + xi] = wz0 * bil0 + wz1 * bil1;
    }
}

// ---------------------------------------------------------------------------
extern "C" void kernel_launch(void* const* d_in, const int* in_sizes, int n_in,
                              void* d_out, int out_size, void* d_ws, size_t ws_size,
                              hipStream_t stream) {
    const float* feature_map = (const float*)d_in[0];  // [4,256,128,128]
    const float* para_code   = (const float*)d_in[1];  // [4,256]
    const float* W1 = (const float*)d_in[2];
    const float* b1 = (const float*)d_in[3];
    const float* Ws = (const float*)d_in[4];
    const float* bs = (const float*)d_in[5];
    const float* Wr = (const float*)d_in[6];
    const float* br = (const float*)d_in[7];
    const float* Wt = (const float*)d_in[8];
    const float* bt = (const float*)d_in[9];

    adaat_fused_kernel<<<BATCH * CH, 1024, 0, stream>>>(
        feature_map, para_code, W1, b1, Ws, bs, Wr, br, Wt, bt, (float*)d_out);
}

// Round 4
// 161.368 us; speedup vs baseline: 1.3575x; 1.3575x over previous
//
#include <hip/hip_runtime.h>
#include <math.h>

#define BATCH 4
#define CH    256   // feature channels == depth of sampled volume
#define HH    128
#define WW    128
#define PC    256   // para channels
#define PI_F  3.14159f
#define PLANE (HH * WW)   // 16384 floats = 64 KiB

// ---------------------------------------------------------------------------
// Fully fused AdaAT, one launch. 512 blocks x 1024 threads; block handles the
// two planes bc = blockIdx*2 + {0,1} (same batch b; 2 | 256 so no straddle).
//
// Key structure (fixes R3's spill + R2's duplicated work):
//  - z-interp folded into staging: LDS holds ONE pre-z-interpolated plane
//    (wz0*pl0 + wz1*pl1), 64 KiB. Trilinear gather becomes bilinear:
//    4 ds_read_b32 + 6 FMA, coords computed once.
//  - staging uses short-lived 16-VGPR chunks (no buffer held across GEMV)
//    -> fits the 64-VGPR budget of launch_bounds(1024,8) = 2 blocks/CU.
//  - latency hiding via co-resident block overlap (one stages, one gathers).
//  - LDS swizzle x ^ ((y&3)<<3): non-linear, keeps float4 runs contiguous;
//    worst realistic gather conflict ~4-way, typical <=2-way (free).
// ---------------------------------------------------------------------------
__global__ __launch_bounds__(1024, 8)
void adaat_fused_kernel(const float* __restrict__ fm,
                        const float* __restrict__ pc,
                        const float* __restrict__ W1, const float* __restrict__ b1,
                        const float* __restrict__ Ws, const float* __restrict__ bs,
                        const float* __restrict__ Wr, const float* __restrict__ br,
                        const float* __restrict__ Wt, const float* __restrict__ bt,
                        float* __restrict__ out) {
    __shared__ float  lds[PLANE];    // 64 KiB plane buffer (also GEMV scratch)
    __shared__ float  p_sh[PC];
    __shared__ float  sh_head[8];
    __shared__ float4 sh_par[2];

    const int t   = threadIdx.x;
    const int bc0 = blockIdx.x * 2;
    const int b   = bc0 >> 8;

    // ---- 1) p = relu(pc @ W1 + b1), 4-way k-split; reduce through lds ----
    {
        const int jj = t & 255;
        const int kk = t >> 8;                      // wave-uniform (256|64-aligned)
        const float* pcb = pc + b * PC + kk * 64;
        const float* w   = W1 + (kk * 64) * PC + jj;
        float acc = 0.0f;
#pragma unroll 8
        for (int i = 0; i < 64; ++i)
            acc = fmaf(pcb[i], w[i * PC], acc);
        lds[t] = acc;
    }
    __syncthreads();
    if (t < 256) {
        const float s = lds[t] + lds[256 + t] + lds[512 + t] + lds[768 + t] + b1[t];
        p_sh[t] = fmaxf(s, 0.0f);
    }
    __syncthreads();

    // ---- 2) head dot-products: wave wv -> channel q = wv>>2, head wv&3 ----
    const int wv = t >> 6;
    const int l  = t & 63;
    if (wv < 8) {
        const int q  = wv >> 2;
        const int h  = wv & 3;
        const int cq = (bc0 + q) & (CH - 1);
        const float* wp;
        int stride;
        if      (h == 0) { wp = Ws + cq;                stride = CH;     }
        else if (h == 1) { wp = Wr + cq;                stride = CH;     }
        else             { wp = Wt + 2 * cq + (h == 3); stride = 2 * CH; }
        float dot = 0.0f;
#pragma unroll
        for (int m = 0; m < 4; ++m) {
            const int k = l + 64 * m;
            dot = fmaf(p_sh[k], wp[(size_t)k * stride], dot);
        }
#pragma unroll
        for (int off = 32; off >= 1; off >>= 1)
            dot += __shfl_xor(dot, off, 64);
        if (l == 0) sh_head[wv] = dot;
    }
    __syncthreads();

    // ---- 3) transcendentals -> fused pixel-space affine constants ----
    if (t < 2) {
        const int cq = (bc0 + t) & (CH - 1);
        const float ds = sh_head[4 * t + 0] + bs[cq];
        const float dr = sh_head[4 * t + 1] + br[cq];
        const float d0 = sh_head[4 * t + 2] + bt[2 * cq];
        const float d1 = sh_head[4 * t + 3] + bt[2 * cq + 1];
        const float s   = 2.0f / (1.0f + expf(-ds));
        const float ang = tanhf(dr) * PI_F;
        float sa, ca;
        sincosf(ang, &sa, &ca);
        const float A  = s * ca, B = s * sa;
        const float Tx = tanhf(d0), Ty = tanhf(d1);
        // ix = cA*x - cB*y + C0 ; iy = cB*x + cA*y + C1  (pixel-space direct)
        sh_par[t] = make_float4(A * (128.0f / 127.0f),
                                B * (128.0f / 127.0f),
                                64.0f * (Tx - A + B) + 63.5f,
                                64.0f * (Ty - A - B) + 63.5f);
    }
    // (visibility of sh_par guaranteed by the staging barrier below)

    const int   xi = l & 7;                 // wave = 8x8 pixel tile
    const int   yj = wv * 8 + (l >> 3);     // 16 waves cover rows 0..127
    const float yf = (float)yj;
    const float* base = fm + (size_t)b * (CH * PLANE);

    for (int it = 0; it < 2; ++it) {
        const int c = (bc0 + it) & (CH - 1);

        // z-interp weights (uniform across block)
        const float iz  = (256.0f / 255.0f) * (float)c - 0.5f;
        const float z0f = floorf(iz);
        const float fz  = iz - z0f;
        const int   z0  = (int)z0f;
        const float wz0 = (z0 >= 0)     ? (1.0f - fz) : 0.0f;
        const float wz1 = (z0 + 1 < CH) ? fz          : 0.0f;
        const float* pl0 = base + (size_t)max(z0, 0)          * PLANE;
        const float* pl1 = base + (size_t)min(z0 + 1, CH - 1) * PLANE;

        __syncthreads();   // it=0: params/GEMV done; it=1: prev gather done

        // ---- 4) stage wz0*pl0 + wz1*pl1 into swizzled LDS (2 short chunks) ----
#pragma unroll
        for (int j = 0; j < 2; ++j) {
            const int f0 = 4 * (t + 1024 * (2 * j));
            const int f1 = 4 * (t + 1024 * (2 * j + 1));
            const float4 a0 = *(const float4*)(pl0 + f0);
            const float4 b0 = *(const float4*)(pl1 + f0);
            const float4 a1 = *(const float4*)(pl0 + f1);
            const float4 b1v = *(const float4*)(pl1 + f1);
            float4 c0, c1;
            c0.x = fmaf(wz0, a0.x, wz1 * b0.x);
            c0.y = fmaf(wz0, a0.y, wz1 * b0.y);
            c0.z = fmaf(wz0, a0.z, wz1 * b0.z);
            c0.w = fmaf(wz0, a0.w, wz1 * b0.w);
            c1.x = fmaf(wz0, a1.x, wz1 * b1v.x);
            c1.y = fmaf(wz0, a1.y, wz1 * b1v.y);
            c1.z = fmaf(wz0, a1.z, wz1 * b1v.z);
            c1.w = fmaf(wz0, a1.w, wz1 * b1v.w);
            const int y0 = f0 >> 7, x0 = f0 & (WW - 1);
            const int y1 = f1 >> 7, x1 = f1 & (WW - 1);
            *(float4*)&lds[y0 * WW + (x0 ^ ((y0 & 3) << 3))] = c0;
            *(float4*)&lds[y1 * WW + (x1 ^ ((y1 & 3) << 3))] = c1;
        }
        __syncthreads();

        // ---- 5) bilinear gather from LDS ----
        const float4 P  = sh_par[it];
        const float  cA = P.x, cB = P.y, C0 = P.z, C1 = P.w;
        float* outp = out + (size_t)(bc0 + it) * PLANE + yj * WW;

#pragma unroll 2
        for (int k = 0; k < 16; ++k) {
            const float xf  = (float)(k * 8 + xi);
            const float ixf = fmaf(cA, xf, fmaf(-cB, yf, C0));
            const float iyf = fmaf(cB, xf, fmaf(cA, yf, C1));
            const float x0f = floorf(ixf);
            const float y0f = floorf(iyf);
            const float fx  = ixf - x0f;
            const float fy  = iyf - y0f;
            // zero-padding masks
            const float mx0 = (x0f >= 0.0f  && x0f < 128.0f) ? (1.0f - fx) : 0.0f;
            const float mx1 = (x0f >= -1.0f && x0f < 127.0f) ? fx          : 0.0f;
            const float my0 = (y0f >= 0.0f  && y0f < 128.0f) ? (1.0f - fy) : 0.0f;
            const float my1 = (y0f >= -1.0f && y0f < 127.0f) ? fy          : 0.0f;

            const int x0i = (int)x0f, y0i = (int)y0f;
            const int xc0 = min(max(x0i,     0), WW - 1);
            const int xc1 = min(max(x0i + 1, 0), WW - 1);
            const int yc0 = min(max(y0i,     0), HH - 1);
            const int yc1 = min(max(y0i + 1, 0), HH - 1);

            const int r0 = yc0 * WW, r1 = yc1 * WW;
            const int s0 = (yc0 & 3) << 3, s1 = (yc1 & 3) << 3;
            const float v00 = lds[r0 + (xc0 ^ s0)];
            const float v01 = lds[r0 + (xc1 ^ s0)];
            const float v10 = lds[r1 + (xc0 ^ s1)];
            const float v11 = lds[r1 + (xc1 ^ s1)];

            outp[k * 8 + xi] = my0 * (mx0 * v00 + mx1 * v01)
                             + my1 * (mx0 * v10 + mx1 * v11);
        }
    }
}

// ---------------------------------------------------------------------------
extern "C" void kernel_launch(void* const* d_in, const int* in_sizes, int n_in,
                              void* d_out, int out_size, void* d_ws, size_t ws_size,
                              hipStream_t stream) {
    const float* feature_map = (const float*)d_in[0];  // [4,256,128,128]
    const float* para_code   = (const float*)d_in[1];  // [4,256]
    const float* W1 = (const float*)d_in[2];
    const float* b1 = (const float*)d_in[3];
    const float* Ws = (const float*)d_in[4];
    const float* bs = (const float*)d_in[5];
    const float* Wr = (const float*)d_in[6];
    const float* br = (const float*)d_in[7];
    const float* Wt = (const float*)d_in[8];
    const float* bt = (const float*)d_in[9];

    adaat_fused_kernel<<<BATCH * CH / 2, 1024, 0, stream>>>(
        feature_map, para_code, W1, b1, Ws, bs, Wr, br, Wt, bt, (float*)d_out);
}